// Round 11
// baseline (42.947 us; speedup 1.0000x reference)
//
#include <hip/hip_runtime.h>

namespace {

typedef float v2f __attribute__((ext_vector_type(2)));

constexpr int kT   = 8;    // timesteps
constexpr int kB   = 256;  // batch
constexpr int kNQ  = 8;    // qubits per circuit
constexpr int kNB  = 8;    // blocks
constexpr int kD   = 64;   // features
constexpr int kNL  = 2;    // quantum layers
constexpr int kCirc = kT * kNB;        // 64 circuits per layer
constexpr int kGates = 2 * kNQ;        // 16 gate slots per circuit
constexpr int kGateF = 8;

// ---------------- Rot-gate precompute ----------------
// slots (d=0,w=0..7) and (d=1,w=0..5): full 2x2 complex gate (8 floats)
// slots (d=1,w=6..7): Hermitian h = g^dag Z g stored as (a, Re b, Im b, 0...)
__global__ void precompute_gates(const float* __restrict__ theta, float* __restrict__ gt) {
    int i = blockIdx.x * blockDim.x + threadIdx.x;
    if (i >= kNL * kCirc * kGates) return;
    int g = i & 15;
    int c = (i >> 4) & 63;
    int l = i >> 10;
    int t = c >> 3, u = c & 7;
    int d = g >> 3, w = g & 7;
    const float* th = theta + ((((t * kNL + l) * kNB + u) * 2 + d) * kNQ + w) * 3;
    float phi = th[0], tht = th[1], omg = th[2];
    float st, ct, sp, cp, sm, cm;
    __sincosf(0.5f * tht, &st, &ct);
    __sincosf(0.5f * (phi + omg), &sp, &cp);
    __sincosf(0.5f * (phi - omg), &sm, &cm);
    const float u00r =  ct * cp, u00i = -ct * sp;
    const float u01r = -st * cm, u01i = -st * sm;
    const float u10r =  st * cm, u10i = -st * sm;
    const float u11r =  ct * cp, u11i =  ct * sp;
    float* o = gt + i * kGateF;
    if (d == 1 && w >= 6) {
        // h = g^dag Z g: h00 = |u00|^2-|u10|^2, h01 = conj(u00)u01 - conj(u10)u11
        o[0] = (u00r * u00r + u00i * u00i) - (u10r * u10r + u10i * u10i);
        o[1] = (u00r * u01r + u00i * u01i) - (u10r * u11r + u10i * u11i);
        o[2] = (u00r * u01i - u00i * u01r) - (u10r * u11i - u10i * u11r);
        o[3] = 0.0f; o[4] = 0.0f; o[5] = 0.0f; o[6] = 0.0f; o[7] = 0.0f;
    } else {
        o[0] = u00r;  o[1] = u00i;
        o[2] = u01r;  o[3] = u01i;
        o[4] = u10r;  o[5] = u10i;
        o[6] = u11r;  o[7] = u11i;
    }
}

// ---------------- shuffle backends ----------------
template <int CTRL>
__device__ __forceinline__ float f_dpp(float x) {
    return __builtin_bit_cast(float, __builtin_amdgcn_update_dpp(
        0, __builtin_bit_cast(int, x), CTRL, 0xF, 0xF, true));
}
constexpr int kDppXor1 = 0xB1;   // quad_perm [1,0,3,2]  = lane^1
constexpr int kDppXor2 = 0x4E;   // quad_perm [2,3,0,1]  = lane^2
constexpr int kDppXor8 = 0x128;  // row_ror:8 (16-lane row) = lane^8  [validated r7/r8]

// partner fetch at lane distance 1<<MODE: 0,1,3 via DPP (VALU); 2,4,5 via shfl (DS).
// permlane16/32_swap is BANNED: 3 failed rounds (r3 builtin, r6 raw asm, r10
// builtin+distinct-reg) — the self-input pair-sum model is wrong on this HW/compiler.
template <int MODE>
__device__ __forceinline__ float lane_partner(float x) {
    if constexpr (MODE == 0) return f_dpp<kDppXor1>(x);
    else if constexpr (MODE == 1) return f_dpp<kDppXor2>(x);
    else if constexpr (MODE == 3) return f_dpp<kDppXor8>(x);
    else if constexpr (MODE == 2) return __shfl_xor(x, 4, 64);
    else if constexpr (MODE == 4) return __shfl_xor(x, 16, 64);
    else return __shfl_xor(x, 32, 64);
}
template <int MODE>
__device__ __forceinline__ v2f partner2(v2f v) {
    v2f r;
    r.x = lane_partner<MODE>(v.x);
    r.y = lane_partner<MODE>(v.y);
    return r;
}

__device__ __forceinline__ v2f sel2(int c, v2f a, v2f b) { return c ? a : b; }

// ---------------- gate helper (2 packed samples, 4 amps/lane) ----------------
// amp index k = (lane<<2)|reg; wire w -> index bit 7-w.
// wires 0..5 -> lane bits 5..0; wires 6,7 -> reg bits 1,0 (folded as Hermitian forms).
template <int MODE>
__device__ __forceinline__ void gate_p(v2f (&re)[4], v2f (&im)[4], int bit,
                                       const float* __restrict__ gp) {
    const float aR = bit ? gp[6] : gp[0];
    const float aI = bit ? gp[7] : gp[1];
    const float bR = bit ? gp[4] : gp[2];
    const float bI = bit ? gp[5] : gp[3];
#pragma unroll
    for (int r = 0; r < 4; ++r) {
        const v2f pre = partner2<MODE>(re[r]);
        const v2f pim = partner2<MODE>(im[r]);
        const v2f mre = re[r], mim = im[r];
        re[r] = aR * mre - aI * mim + bR * pre - bI * pim;   // v_pk_fma_f32 chain
        im[r] = aR * mim + aI * mre + bR * pim + bI * pre;
    }
}

// ---------------- one circuit sim: 2 packed samples, 3 Walsh streams out ----------------
// State after AngleEmbedding + depth-0 Rot + CNOT-ring1 built directly as a permuted
// spinor product; depth-1 Rot gates on lane-bit wires; reg-bit wires (6,7) folded as
// Hermitian quadratic forms; CNOT-ring2 folded into Walsh parities of the reduction.
__device__ __forceinline__ void sim2p(const float (&ang)[2][8],
                                      const float* __restrict__ g0,
                                      const float* __restrict__ g1,
                                      int lane, const v2f (&sv)[6],
                                      v2f& WPo, v2f& WR1o, v2f& WR0o) {
    const int l0 = lane & 1,        l1 = (lane >> 1) & 1, l2 = (lane >> 2) & 1;
    const int l3 = (lane >> 3) & 1, l4 = (lane >> 4) & 1, l5 = (lane >> 5) & 1;

    v2f re[4], im[4];
    {
        // per-wire spinor after RY(ang) then d0 Rot, packed over samples
        v2f spr[8][2], spi[8][2];
#pragma unroll
        for (int w = 0; w < 8; ++w) {
            float s0, c0, s1, c1;
            __sincosf(0.5f * ang[0][w], &s0, &c0);
            __sincosf(0.5f * ang[1][w], &s1, &c1);
            const v2f cs = {c0, c1}, sn = {s0, s1};
            const float* gp = g0 + w * kGateF;
            spr[w][0] = gp[0] * cs + gp[2] * sn;
            spi[w][0] = gp[1] * cs + gp[3] * sn;
            spr[w][1] = gp[4] * cs + gp[6] * sn;
            spi[w][1] = gp[5] * cs + gp[7] * sn;
        }
        // ring1 inverse bit map (x = pre-ring1 wire bits; (lane,reg) = post-ring1):
        //  x0=l5^r0  x1=l5^l4^r0  x2=l4^l3  x3=l3^l2  x4=l2^l1  x5=l1^l0
        //  x6=l0^r1  x7=r1^r0
        const int x2 = l4 ^ l3, x3 = l3 ^ l2, x4 = l2 ^ l1, x5 = l1 ^ l0;
        v2f t1r, t1i, t2r, t2i;
        {
            const v2f ar = sel2(x2, spr[2][1], spr[2][0]), ai = sel2(x2, spi[2][1], spi[2][0]);
            const v2f br = sel2(x3, spr[3][1], spr[3][0]), bi = sel2(x3, spi[3][1], spi[3][0]);
            t1r = ar * br - ai * bi; t1i = ar * bi + ai * br;
        }
        {
            const v2f ar = sel2(x4, spr[4][1], spr[4][0]), ai = sel2(x4, spi[4][1], spi[4][0]);
            const v2f br = sel2(x5, spr[5][1], spr[5][0]), bi = sel2(x5, spi[5][1], spi[5][0]);
            t2r = ar * br - ai * bi; t2i = ar * bi + ai * br;
        }
        const v2f Lr = t1r * t2r - t1i * t2i, Li = t1r * t2i + t1i * t2r;
        // Q(r0) = s0[l5^r0] * s1[l5^l4^r0]
        const int xa = l5, xb = l5 ^ l4;
        const v2f a0r = sel2(xa, spr[0][1], spr[0][0]), a0i = sel2(xa, spi[0][1], spi[0][0]);
        const v2f a1r = sel2(xa, spr[0][0], spr[0][1]), a1i = sel2(xa, spi[0][0], spi[0][1]);
        const v2f b0r = sel2(xb, spr[1][1], spr[1][0]), b0i = sel2(xb, spi[1][1], spi[1][0]);
        const v2f b1r = sel2(xb, spr[1][0], spr[1][1]), b1i = sel2(xb, spi[1][0], spi[1][1]);
        const v2f Q0r = a0r * b0r - a0i * b0i, Q0i = a0r * b0i + a0i * b0r;
        const v2f Q1r = a1r * b1r - a1i * b1i, Q1i = a1r * b1i + a1i * b1r;
        // R(r1) = s6[l0^r1]; S(r0,r1) = s7[r1^r0]
        const v2f R0r = sel2(l0, spr[6][1], spr[6][0]), R0i = sel2(l0, spi[6][1], spi[6][0]);
        const v2f R1r = sel2(l0, spr[6][0], spr[6][1]), R1i = sel2(l0, spi[6][0], spi[6][1]);
        const v2f S0r = spr[7][0], S0i = spi[7][0];
        const v2f S1r = spr[7][1], S1i = spi[7][1];
        v2f RSr[4], RSi[4];
        RSr[0] = R0r * S0r - R0i * S0i; RSi[0] = R0r * S0i + R0i * S0r;  // r=0
        RSr[1] = R0r * S1r - R0i * S1i; RSi[1] = R0r * S1i + R0i * S1r;  // r=1
        RSr[2] = R1r * S1r - R1i * S1i; RSi[2] = R1r * S1i + R1i * S1r;  // r=2
        RSr[3] = R1r * S0r - R1i * S0i; RSi[3] = R1r * S0i + R1i * S0r;  // r=3
        const v2f LQ0r = Lr * Q0r - Li * Q0i, LQ0i = Lr * Q0i + Li * Q0r;
        const v2f LQ1r = Lr * Q1r - Li * Q1i, LQ1i = Lr * Q1i + Li * Q1r;
        re[0] = LQ0r * RSr[0] - LQ0i * RSi[0]; im[0] = LQ0r * RSi[0] + LQ0i * RSr[0];
        re[1] = LQ1r * RSr[1] - LQ1i * RSi[1]; im[1] = LQ1r * RSi[1] + LQ1i * RSr[1];
        re[2] = LQ0r * RSr[2] - LQ0i * RSi[2]; im[2] = LQ0r * RSi[2] + LQ0i * RSr[2];
        re[3] = LQ1r * RSr[3] - LQ1i * RSi[3]; im[3] = LQ1r * RSi[3] + LQ1i * RSr[3];
    }

    // --- depth-1 Rot gates on lane-bit wires (wire w on lane bit 5-w) ---
    gate_p<5>(re, im, l5, g1 + 0 * kGateF);     // wire0: xor32 (shfl)
    gate_p<4>(re, im, l4, g1 + 1 * kGateF);     // wire1: xor16 (shfl)
    gate_p<3>(re, im, l3, g1 + 2 * kGateF);     // wire2: xor8 (DPP row_ror:8)
    gate_p<2>(re, im, l2, g1 + 3 * kGateF);     // wire3: xor4 (shfl)
    gate_p<1>(re, im, l1, g1 + 4 * kGateF);     // wire4: xor2 (DPP)
    gate_p<0>(re, im, l0, g1 + 5 * kGateF);     // wire5: xor1 (DPP)

    // --- reg-bit wires via Hermitian forms (packed) ---
    const v2f p0 = re[0] * re[0] + im[0] * im[0];
    const v2f p1 = re[1] * re[1] + im[1] * im[1];
    const v2f p2 = re[2] * re[2] + im[2] * im[2];
    const v2f p3 = re[3] * re[3] + im[3] * im[3];
    v2f P = (p0 + p1) + (p2 + p3);
    const float* h6 = g1 + 6 * kGateF;
    const float* h7 = g1 + 7 * kGateF;
    const v2f z1r = re[0] * re[2] + im[0] * im[2] + re[1] * re[3] + im[1] * im[3];
    const v2f z1i = re[0] * im[2] - im[0] * re[2] + re[1] * im[3] - im[1] * re[3];
    v2f R1 = h6[0] * ((p0 + p1) - (p2 + p3)) + 2.0f * (h6[1] * z1r - h6[2] * z1i);
    const v2f z0r = re[0] * re[1] + im[0] * im[1] + re[2] * re[3] + im[2] * im[3];
    const v2f z0i = re[0] * im[1] - im[0] * re[1] + re[2] * im[3] - im[2] * re[3];
    v2f R0 = h7[0] * ((p0 - p1) + (p2 - p3)) + 2.0f * (h7[1] * z0r - h7[2] * z0i);

    // --- ring2 folded into Walsh parities: full WHT butterfly, W[m] at lane m ---
    // per level: v' = partner + sv[q] * v  (sv = packed ±1 from lane bit q)
#pragma unroll
    for (int st = 0; st < 3; ++st) {
        v2f v = (st == 0) ? P : (st == 1) ? R1 : R0;
        v2f d;
        d = partner2<0>(v); v = d + sv[0] * v;
        d = partner2<1>(v); v = d + sv[1] * v;
        d = partner2<2>(v); v = d + sv[2] * v;
        d = partner2<3>(v); v = d + sv[3] * v;
        d = partner2<4>(v); v = d + sv[4] * v;
        d = partner2<5>(v); v = d + sv[5] * v;
        if (st == 0) P = v; else if (st == 1) R1 = v; else R0 = v;
    }
    WPo = P; WR1o = R1; WR0o = R0;
}

// scatter the 8 expvals (E_w = Walsh coeffs at fixed lanes) to e[0..7]
// masks: E0:R1@10  E1:R0@5  E2:P@40  E3:P@20  E4:P@42  E5:P@21  E6:R1@42  E7:R0@21
template <typename PT>
__device__ __forceinline__ void scatter_ev(PT e, int lane, float P, float R1, float R0) {
    if (lane == 10) e[0] = R1;
    if (lane ==  5) e[1] = R0;
    if (lane == 40) e[2] = P;
    if (lane == 20) e[3] = P;
    if (lane == 42) { e[4] = P; e[6] = R1; }
    if (lane == 21) { e[5] = P; e[7] = R0; }
}

// ---------------- fused both-layer kernel ----------------
// block = 512 threads = 8 waves = the 8 circuits of one (t, sample-pair);
// 2 packed samples per wave; layer-0 results exchanged through 512 B of LDS.
// launch_bounds(512, 8): force <=64 VGPR/wave -> 8 waves/SIMD (32/CU) residency.
__global__ __launch_bounds__(512, 8) void fused_kernel(const float* __restrict__ x,
                                                       const float* __restrict__ gt,
                                                       float* __restrict__ out) {
    const int widx = __builtin_amdgcn_readfirstlane(threadIdx.x >> 6);  // circuit u
    const int lane = threadIdx.x & 63;
    const int tt = blockIdx.x >> 7;          // timestep
    const int b0 = (blockIdx.x & 127) << 1;  // first sample of pair

    __shared__ float exch[2][8][8];          // [sample][block i][wire w]

    v2f sv[6];
#pragma unroll
    for (int q = 0; q < 6; ++q) {
        const float s = ((lane >> q) & 1) ? -1.0f : 1.0f;
        sv[q].x = s; sv[q].y = s;
    }

    const int c = tt * kNB + widx;
    v2f WP, WR1, WR0;
    float ang[2][8];

    // ---- phase 0: layer-0 circuit (t, widx), samples b0, b0+1 ----
    {
        const float* g0 = gt + (size_t)c * kGates * kGateF;
        const float* g1 = g0 + 8 * kGateF;
#pragma unroll
        for (int s = 0; s < 2; ++s) {
            const float* ab = x + (((b0 + s) * kT + tt) * kD + widx * kNQ);
#pragma unroll
            for (int w = 0; w < 8; ++w) ang[s][w] = ab[w];
        }
        sim2p(ang, g0, g1, lane, sv, WP, WR1, WR0);
        scatter_ev(&exch[0][widx][0], lane, WP.x, WR1.x, WR0.x);
        scatter_ev(&exch[1][widx][0], lane, WP.y, WR1.y, WR0.y);
    }
    __syncthreads();
    // ---- phase 1: layer-1 circuit (t, widx) gathers feature widx of every block ----
    {
        const float* g0 = gt + (size_t)(kCirc + c) * kGates * kGateF;
        const float* g1 = g0 + 8 * kGateF;
#pragma unroll
        for (int s = 0; s < 2; ++s)
#pragma unroll
            for (int i = 0; i < 8; ++i) ang[s][i] = exch[s][i][widx];
        sim2p(ang, g0, g1, lane, sv, WP, WR1, WR0);
        scatter_ev(out + (((b0 + 0) * kT + tt) * kD + widx * kNQ), lane, WP.x, WR1.x, WR0.x);
        scatter_ev(out + (((b0 + 1) * kT + tt) * kD + widx * kNQ), lane, WP.y, WR1.y, WR0.y);
    }
}

}  // namespace

extern "C" void kernel_launch(void* const* d_in, const int* in_sizes, int n_in,
                              void* d_out, int out_size, void* d_ws, size_t ws_size,
                              hipStream_t stream) {
    const float* x     = (const float*)d_in[0];   // (B, T, D) fp32
    const float* theta = (const float*)d_in[1];   // (T, NL, NB, DEPTH, NQ, 3) fp32
    float* out = (float*)d_out;                   // (B, T, D) fp32

    float* gt = (float*)d_ws;                     // gate table: 2*64*16*8 floats (64 KB)

    precompute_gates<<<(kNL * kCirc * kGates + 255) / 256, 256, 0, stream>>>(theta, gt);
    // 8 timesteps x 128 sample-pairs; 512 threads = 8 circuits x 2 packed samples/wave
    fused_kernel<<<kT * (kB / 2), 512, 0, stream>>>(x, gt, out);
}

// Round 12
// 38.504 us; speedup vs baseline: 1.1154x; 1.1154x over previous
//
#include <hip/hip_runtime.h>

namespace {

typedef float v2f __attribute__((ext_vector_type(2)));

constexpr int kT   = 8;    // timesteps
constexpr int kB   = 256;  // batch
constexpr int kNQ  = 8;    // qubits per circuit
constexpr int kNB  = 8;    // blocks
constexpr int kD   = 64;   // features
constexpr int kNL  = 2;    // quantum layers
constexpr int kCirc = kT * kNB;        // 64 circuits per layer
constexpr int kGates = 2 * kNQ;        // 16 gate slots per circuit
constexpr int kGateF = 8;

// ---------------- Rot-gate precompute ----------------
// slots (d=0,w=0..7) and (d=1,w=0..5): full 2x2 complex gate (8 floats)
// slots (d=1,w=6..7): Hermitian h = g^dag Z g stored as (a, Re b, Im b, 0...)
__global__ void precompute_gates(const float* __restrict__ theta, float* __restrict__ gt) {
    int i = blockIdx.x * blockDim.x + threadIdx.x;
    if (i >= kNL * kCirc * kGates) return;
    int g = i & 15;
    int c = (i >> 4) & 63;
    int l = i >> 10;
    int t = c >> 3, u = c & 7;
    int d = g >> 3, w = g & 7;
    const float* th = theta + ((((t * kNL + l) * kNB + u) * 2 + d) * kNQ + w) * 3;
    float phi = th[0], tht = th[1], omg = th[2];
    float st, ct, sp, cp, sm, cm;
    __sincosf(0.5f * tht, &st, &ct);
    __sincosf(0.5f * (phi + omg), &sp, &cp);
    __sincosf(0.5f * (phi - omg), &sm, &cm);
    const float u00r =  ct * cp, u00i = -ct * sp;
    const float u01r = -st * cm, u01i = -st * sm;
    const float u10r =  st * cm, u10i = -st * sm;
    const float u11r =  ct * cp, u11i =  ct * sp;
    float* o = gt + i * kGateF;
    if (d == 1 && w >= 6) {
        // h = g^dag Z g: h00 = |u00|^2-|u10|^2, h01 = conj(u00)u01 - conj(u10)u11
        o[0] = (u00r * u00r + u00i * u00i) - (u10r * u10r + u10i * u10i);
        o[1] = (u00r * u01r + u00i * u01i) - (u10r * u11r + u10i * u11i);
        o[2] = (u00r * u01i - u00i * u01r) - (u10r * u11i - u10i * u11r);
        o[3] = 0.0f; o[4] = 0.0f; o[5] = 0.0f; o[6] = 0.0f; o[7] = 0.0f;
    } else {
        o[0] = u00r;  o[1] = u00i;
        o[2] = u01r;  o[3] = u01i;
        o[4] = u10r;  o[5] = u10i;
        o[6] = u11r;  o[7] = u11i;
    }
}

// ---------------- shuffle backends ----------------
template <int CTRL>
__device__ __forceinline__ float f_dpp(float x) {
    return __builtin_bit_cast(float, __builtin_amdgcn_update_dpp(
        0, __builtin_bit_cast(int, x), CTRL, 0xF, 0xF, true));
}
constexpr int kDppXor1 = 0xB1;   // quad_perm [1,0,3,2]  = lane^1
constexpr int kDppXor2 = 0x4E;   // quad_perm [2,3,0,1]  = lane^2
constexpr int kDppXor8 = 0x128;  // row_ror:8 (16-lane row) = lane^8  [validated r7/r8]

// partner fetch at lane distance 1<<MODE: 0,1,3 via DPP (VALU); 2,4,5 via shfl (DS).
// permlane16/32_swap is BANNED: 3 failed rounds (r3, r6, r10).
template <int MODE>
__device__ __forceinline__ float lane_partner(float x) {
    if constexpr (MODE == 0) return f_dpp<kDppXor1>(x);
    else if constexpr (MODE == 1) return f_dpp<kDppXor2>(x);
    else if constexpr (MODE == 3) return f_dpp<kDppXor8>(x);
    else if constexpr (MODE == 2) return __shfl_xor(x, 4, 64);
    else if constexpr (MODE == 4) return __shfl_xor(x, 16, 64);
    else return __shfl_xor(x, 32, 64);
}
template <int MODE>
__device__ __forceinline__ v2f partner2(v2f v) {
    v2f r;
    r.x = lane_partner<MODE>(v.x);
    r.y = lane_partner<MODE>(v.y);
    return r;
}

__device__ __forceinline__ v2f sel2(int c, v2f a, v2f b) { return c ? a : b; }

// per-wire spinor after RY(ang) then d0 Rot, packed over samples (compile-time wire W)
template <int W>
__device__ __forceinline__ void spinor(const float (&ang)[2][8], const float* __restrict__ g0,
                                       v2f& r0, v2f& i0, v2f& r1, v2f& i1) {
    float s0, c0, s1, c1;
    __sincosf(0.5f * ang[0][W], &s0, &c0);
    __sincosf(0.5f * ang[1][W], &s1, &c1);
    const v2f cs = {c0, c1}, sn = {s0, s1};
    const float* gp = g0 + W * kGateF;
    r0 = gp[0] * cs + gp[2] * sn;
    i0 = gp[1] * cs + gp[3] * sn;
    r1 = gp[4] * cs + gp[6] * sn;
    i1 = gp[5] * cs + gp[7] * sn;
}

// ---------------- gate helper (2 packed samples, 4 amps/lane) ----------------
// amp index k = (lane<<2)|reg; wire w -> index bit 7-w.
// wires 0..5 -> lane bits 5..0; wires 6,7 -> reg bits 1,0 (folded as Hermitian forms).
template <int MODE>
__device__ __forceinline__ void gate_p(v2f (&re)[4], v2f (&im)[4], int bit,
                                       const float* __restrict__ gp) {
    const float aR = bit ? gp[6] : gp[0];
    const float aI = bit ? gp[7] : gp[1];
    const float bR = bit ? gp[4] : gp[2];
    const float bI = bit ? gp[5] : gp[3];
#pragma unroll
    for (int r = 0; r < 4; ++r) {
        const v2f pre = partner2<MODE>(re[r]);
        const v2f pim = partner2<MODE>(im[r]);
        const v2f mre = re[r], mim = im[r];
        re[r] = aR * mre - aI * mim + bR * pre - bI * pim;   // v_pk_fma_f32 chain
        im[r] = aR * mim + aI * mre + bR * pim + bI * pre;
    }
}

// ---------------- one circuit sim: 2 packed samples, 3 Walsh streams out ----------------
// State after AngleEmbedding + depth-0 Rot + CNOT-ring1 built directly as a permuted
// spinor product (spinors built/consumed per wire-pair to cap register liveness);
// depth-1 Rot gates on lane-bit wires; reg-bit wires (6,7) folded as Hermitian
// quadratic forms; CNOT-ring2 folded into Walsh parities of the reduction.
__device__ __forceinline__ void sim2p(const float (&ang)[2][8],
                                      const float* __restrict__ g0,
                                      const float* __restrict__ g1,
                                      int lane, const v2f (&sv)[6],
                                      v2f& WPo, v2f& WR1o, v2f& WR0o) {
    const int l0 = lane & 1,        l1 = (lane >> 1) & 1, l2 = (lane >> 2) & 1;
    const int l3 = (lane >> 3) & 1, l4 = (lane >> 4) & 1, l5 = (lane >> 5) & 1;

    // ring1 inverse bit map (x = pre-ring1 wire bits; (lane,reg) = post-ring1):
    //  x0=l5^r0  x1=l5^l4^r0  x2=l4^l3  x3=l3^l2  x4=l2^l1  x5=l1^l0
    //  x6=l0^r1  x7=r1^r0
    const int x2 = l4 ^ l3, x3 = l3 ^ l2, x4 = l2 ^ l1, x5 = l1 ^ l0;

    // --- L = s2[x2]*s3[x3]*s4[x4]*s5[x5]  (<=2 wires' spinors live at a time) ---
    v2f Lr, Li;
    {
        v2f p0r, p0i, p1r, p1i, q0r, q0i, q1r, q1i;
        spinor<2>(ang, g0, p0r, p0i, p1r, p1i);
        spinor<3>(ang, g0, q0r, q0i, q1r, q1i);
        const v2f ar = sel2(x2, p1r, p0r), ai = sel2(x2, p1i, p0i);
        const v2f br = sel2(x3, q1r, q0r), bi = sel2(x3, q1i, q0i);
        const v2f t1r = ar * br - ai * bi, t1i = ar * bi + ai * br;
        spinor<4>(ang, g0, p0r, p0i, p1r, p1i);
        spinor<5>(ang, g0, q0r, q0i, q1r, q1i);
        const v2f cr = sel2(x4, p1r, p0r), ci = sel2(x4, p1i, p0i);
        const v2f dr = sel2(x5, q1r, q0r), di = sel2(x5, q1i, q0i);
        const v2f t2r = cr * dr - ci * di, t2i = cr * di + ci * dr;
        Lr = t1r * t2r - t1i * t2i;  Li = t1r * t2i + t1i * t2r;
    }
    // --- LQ(r0) = L * s0[l5^r0] * s1[l5^l4^r0] ---
    v2f LQ0r, LQ0i, LQ1r, LQ1i;
    {
        v2f s0r, s0i, s1r, s1i, u0r, u0i, u1r, u1i;
        spinor<0>(ang, g0, s0r, s0i, s1r, s1i);
        spinor<1>(ang, g0, u0r, u0i, u1r, u1i);
        const int xa = l5, xb = l5 ^ l4;
        const v2f a0r = sel2(xa, s1r, s0r), a0i = sel2(xa, s1i, s0i);
        const v2f a1r = sel2(xa, s0r, s1r), a1i = sel2(xa, s0i, s1i);
        const v2f b0r = sel2(xb, u1r, u0r), b0i = sel2(xb, u1i, u0i);
        const v2f b1r = sel2(xb, u0r, u1r), b1i = sel2(xb, u0i, u1i);
        const v2f Q0r = a0r * b0r - a0i * b0i, Q0i = a0r * b0i + a0i * b0r;
        const v2f Q1r = a1r * b1r - a1i * b1i, Q1i = a1r * b1i + a1i * b1r;
        LQ0r = Lr * Q0r - Li * Q0i;  LQ0i = Lr * Q0i + Li * Q0r;
        LQ1r = Lr * Q1r - Li * Q1i;  LQ1i = Lr * Q1i + Li * Q1r;
    }
    // --- amp[r] = LQ(r0) * R(r1)*S(r1^r0);  R = s6[l0^r1], S = s7[r1^r0] ---
    v2f re[4], im[4];
    {
        v2f r6a, i6a, r6b, i6b, r7a, i7a, r7b, i7b;
        spinor<6>(ang, g0, r6a, i6a, r6b, i6b);
        spinor<7>(ang, g0, r7a, i7a, r7b, i7b);
        const v2f R0r = sel2(l0, r6b, r6a), R0i = sel2(l0, i6b, i6a);
        const v2f R1r = sel2(l0, r6a, r6b), R1i = sel2(l0, i6a, i6b);
        v2f RSr[4], RSi[4];
        RSr[0] = R0r * r7a - R0i * i7a;  RSi[0] = R0r * i7a + R0i * r7a;  // r=0: R0*S0
        RSr[1] = R0r * r7b - R0i * i7b;  RSi[1] = R0r * i7b + R0i * r7b;  // r=1: R0*S1
        RSr[2] = R1r * r7b - R1i * i7b;  RSi[2] = R1r * i7b + R1i * r7b;  // r=2: R1*S1
        RSr[3] = R1r * r7a - R1i * i7a;  RSi[3] = R1r * i7a + R1i * r7a;  // r=3: R1*S0
        re[0] = LQ0r * RSr[0] - LQ0i * RSi[0]; im[0] = LQ0r * RSi[0] + LQ0i * RSr[0];
        re[1] = LQ1r * RSr[1] - LQ1i * RSi[1]; im[1] = LQ1r * RSi[1] + LQ1i * RSr[1];
        re[2] = LQ0r * RSr[2] - LQ0i * RSi[2]; im[2] = LQ0r * RSi[2] + LQ0i * RSr[2];
        re[3] = LQ1r * RSr[3] - LQ1i * RSi[3]; im[3] = LQ1r * RSi[3] + LQ1i * RSr[3];
    }

    // --- depth-1 Rot gates on lane-bit wires (wire w on lane bit 5-w) ---
    gate_p<5>(re, im, l5, g1 + 0 * kGateF);     // wire0: xor32 (shfl)
    gate_p<4>(re, im, l4, g1 + 1 * kGateF);     // wire1: xor16 (shfl)
    gate_p<3>(re, im, l3, g1 + 2 * kGateF);     // wire2: xor8 (DPP row_ror:8)
    gate_p<2>(re, im, l2, g1 + 3 * kGateF);     // wire3: xor4 (shfl)
    gate_p<1>(re, im, l1, g1 + 4 * kGateF);     // wire4: xor2 (DPP)
    gate_p<0>(re, im, l0, g1 + 5 * kGateF);     // wire5: xor1 (DPP)

    // --- reg-bit wires via Hermitian forms (packed) ---
    const v2f p0 = re[0] * re[0] + im[0] * im[0];
    const v2f p1 = re[1] * re[1] + im[1] * im[1];
    const v2f p2 = re[2] * re[2] + im[2] * im[2];
    const v2f p3 = re[3] * re[3] + im[3] * im[3];
    v2f P = (p0 + p1) + (p2 + p3);
    const float* h6 = g1 + 6 * kGateF;
    const float* h7 = g1 + 7 * kGateF;
    const v2f z1r = re[0] * re[2] + im[0] * im[2] + re[1] * re[3] + im[1] * im[3];
    const v2f z1i = re[0] * im[2] - im[0] * re[2] + re[1] * im[3] - im[1] * re[3];
    v2f R1 = h6[0] * ((p0 + p1) - (p2 + p3)) + 2.0f * (h6[1] * z1r - h6[2] * z1i);
    const v2f z0r = re[0] * re[1] + im[0] * im[1] + re[2] * re[3] + im[2] * im[3];
    const v2f z0i = re[0] * im[1] - im[0] * re[1] + re[2] * im[3] - im[2] * re[3];
    v2f R0 = h7[0] * ((p0 - p1) + (p2 - p3)) + 2.0f * (h7[1] * z0r - h7[2] * z0i);

    // --- ring2 folded into Walsh parities: full WHT butterfly, W[m] at lane m ---
    // per level: v' = partner + sv[q] * v  (sv = packed ±1 from lane bit q)
#pragma unroll
    for (int st = 0; st < 3; ++st) {
        v2f v = (st == 0) ? P : (st == 1) ? R1 : R0;
        v2f d;
        d = partner2<0>(v); v = d + sv[0] * v;
        d = partner2<1>(v); v = d + sv[1] * v;
        d = partner2<2>(v); v = d + sv[2] * v;
        d = partner2<3>(v); v = d + sv[3] * v;
        d = partner2<4>(v); v = d + sv[4] * v;
        d = partner2<5>(v); v = d + sv[5] * v;
        if (st == 0) P = v; else if (st == 1) R1 = v; else R0 = v;
    }
    WPo = P; WR1o = R1; WR0o = R0;
}

// scatter the 8 expvals (E_w = Walsh coeffs at fixed lanes), element stride STRIDE
// masks: E0:R1@10  E1:R0@5  E2:P@40  E3:P@20  E4:P@42  E5:P@21  E6:R1@42  E7:R0@21
template <int STRIDE, typename PT>
__device__ __forceinline__ void scatter_ev(PT e, int lane, float P, float R1, float R0) {
    if (lane == 10) e[0 * STRIDE] = R1;
    if (lane ==  5) e[1 * STRIDE] = R0;
    if (lane == 40) e[2 * STRIDE] = P;
    if (lane == 20) e[3 * STRIDE] = P;
    if (lane == 42) { e[4 * STRIDE] = P; e[6 * STRIDE] = R1; }
    if (lane == 21) { e[5 * STRIDE] = P; e[7 * STRIDE] = R0; }
}

// ---------------- fused both-layer kernel ----------------
// block = 512 threads = 8 waves = the 8 circuits of one (t, sample-pair);
// 2 packed samples per wave; layer-0 results exchanged through 512 B of LDS.
// exch layout [sample][wire][block] -> phase-1 angle gather is 2x float4 reads.
// launch_bounds(512, 6): cap ~85 VGPR -> 6 waves/SIMD (restructured liveness fits).
__global__ __launch_bounds__(512, 6) void fused_kernel(const float* __restrict__ x,
                                                       const float* __restrict__ gt,
                                                       float* __restrict__ out) {
    const int widx = __builtin_amdgcn_readfirstlane(threadIdx.x >> 6);  // circuit u
    const int lane = threadIdx.x & 63;
    const int tt = blockIdx.x >> 7;          // timestep
    const int b0 = (blockIdx.x & 127) << 1;  // first sample of pair

    __shared__ float exch[2][8][8];          // [sample][wire][block]

    v2f sv[6];
#pragma unroll
    for (int q = 0; q < 6; ++q) {
        const float s = ((lane >> q) & 1) ? -1.0f : 1.0f;
        sv[q].x = s; sv[q].y = s;
    }

    const int c = tt * kNB + widx;
    v2f WP, WR1, WR0;
    float ang[2][8];

    // ---- phase 0: layer-0 circuit (t, widx), samples b0, b0+1 ----
    {
        const float* g0 = gt + (size_t)c * kGates * kGateF;
        const float* g1 = g0 + 8 * kGateF;
#pragma unroll
        for (int s = 0; s < 2; ++s) {
            const float* ab = x + (((b0 + s) * kT + tt) * kD + widx * kNQ);
#pragma unroll
            for (int w = 0; w < 8; ++w) ang[s][w] = ab[w];
        }
        sim2p(ang, g0, g1, lane, sv, WP, WR1, WR0);
        scatter_ev<8>(&exch[0][0][widx], lane, WP.x, WR1.x, WR0.x);
        scatter_ev<8>(&exch[1][0][widx], lane, WP.y, WR1.y, WR0.y);
    }
    __syncthreads();
    // ---- phase 1: layer-1 circuit (t, widx) gathers feature widx of every block ----
    {
        const float* g0 = gt + (size_t)(kCirc + c) * kGates * kGateF;
        const float* g1 = g0 + 8 * kGateF;
#pragma unroll
        for (int s = 0; s < 2; ++s) {
            const float4 v0 = *reinterpret_cast<const float4*>(&exch[s][widx][0]);
            const float4 v1 = *reinterpret_cast<const float4*>(&exch[s][widx][4]);
            ang[s][0] = v0.x; ang[s][1] = v0.y; ang[s][2] = v0.z; ang[s][3] = v0.w;
            ang[s][4] = v1.x; ang[s][5] = v1.y; ang[s][6] = v1.z; ang[s][7] = v1.w;
        }
        sim2p(ang, g0, g1, lane, sv, WP, WR1, WR0);
        scatter_ev<1>(out + (((b0 + 0) * kT + tt) * kD + widx * kNQ), lane, WP.x, WR1.x, WR0.x);
        scatter_ev<1>(out + (((b0 + 1) * kT + tt) * kD + widx * kNQ), lane, WP.y, WR1.y, WR0.y);
    }
}

}  // namespace

extern "C" void kernel_launch(void* const* d_in, const int* in_sizes, int n_in,
                              void* d_out, int out_size, void* d_ws, size_t ws_size,
                              hipStream_t stream) {
    const float* x     = (const float*)d_in[0];   // (B, T, D) fp32
    const float* theta = (const float*)d_in[1];   // (T, NL, NB, DEPTH, NQ, 3) fp32
    float* out = (float*)d_out;                   // (B, T, D) fp32

    float* gt = (float*)d_ws;                     // gate table: 2*64*16*8 floats (64 KB)

    precompute_gates<<<(kNL * kCirc * kGates + 255) / 256, 256, 0, stream>>>(theta, gt);
    // 8 timesteps x 128 sample-pairs; 512 threads = 8 circuits x 2 packed samples/wave
    fused_kernel<<<kT * (kB / 2), 512, 0, stream>>>(x, gt, out);
}